// Round 9
// baseline (462.709 us; speedup 1.0000x reference)
//
#include <hip/hip_runtime.h>
#include <hip/hip_bf16.h>

typedef __attribute__((ext_vector_type(8))) short short8;
typedef __attribute__((ext_vector_type(4))) short short4v;
typedef __attribute__((ext_vector_type(4))) float float4v;

#define MFMA16(a, b, c) __builtin_amdgcn_mfma_f32_16x16x32_bf16(a, b, c, 0, 0, 0)

__device__ __forceinline__ short f2bf(float f) {
    __hip_bfloat16 hb = __float2bfloat16(f);
    return *reinterpret_cast<short*>(&hb);
}

// ---------------------------------------------------------------------------
// Kernel 0: W transpose+convert.  W[512][1024] f32 -> Wt[1024][512] bf16.
// ---------------------------------------------------------------------------
__global__ __launch_bounds__(256) void wt_kernel(
    const float* __restrict__ Wn, const float* __restrict__ Wr,
    __hip_bfloat16* __restrict__ Wtn, __hip_bfloat16* __restrict__ Wtr)
{
    const int c0 = blockIdx.x * 64;
    const int k0 = blockIdx.y * 64;
    const int g  = blockIdx.z;
    const float* W = g ? Wr : Wn;
    __hip_bfloat16* Wt = g ? Wtr : Wtn;

    __shared__ short lds[64][72];
    const int t = threadIdx.x;
    {
        const int i  = t >> 2;
        const int j0 = (t & 3) * 16;
        const float* p = W + (size_t)(k0 + i) * 1024 + c0 + j0;
        #pragma unroll
        for (int jj = 0; jj < 16; ++jj)
            lds[j0 + jj][i] = f2bf(p[jj]);
    }
    __syncthreads();
    {
        const int j  = t >> 2;
        const int i0 = (t & 3) * 16;
        __hip_bfloat16* q = Wt + (size_t)(c0 + j) * 512 + k0 + i0;
        short8 v0 = *reinterpret_cast<const short8*>(&lds[j][i0]);
        short8 v1 = *reinterpret_cast<const short8*>(&lds[j][i0 + 8]);
        *reinterpret_cast<short8*>(q)     = v0;
        *reinterpret_cast<short8*>(q + 8) = v1;
    }
}

// ---------------------------------------------------------------------------
// Kernel 1: prep.  nv/rv f32 -> Vt [b][h][64][1024] bf16 + Abf [b][n][512] bf16
// ---------------------------------------------------------------------------
__global__ __launch_bounds__(256) void prep_kernel(
    const float* __restrict__ nv, const float* __restrict__ rv,
    __hip_bfloat16* __restrict__ Vtn, __hip_bfloat16* __restrict__ Vtr,
    __hip_bfloat16* __restrict__ An,  __hip_bfloat16* __restrict__ Ar)
{
    const int ntile = blockIdx.x & 15;
    const int src   = blockIdx.x >> 4;
    const int h     = blockIdx.y;
    const int b     = blockIdx.z;
    const float* V  = src ? rv : nv;
    __hip_bfloat16* Vt = src ? Vtr : Vtn;
    __hip_bfloat16* Ab = src ? Ar  : An;

    __shared__ short lds[64][72];
    const int t  = threadIdx.x;
    const int n0 = ntile * 64;
    {
        const int i  = t >> 2;
        const int j0 = (t & 3) * 16;
        const float* p = V + ((size_t)(b * 1024) + n0 + i) * 512 + h * 64 + j0;
        short8 a0, a1;
        #pragma unroll
        for (int jj = 0; jj < 8; ++jj) {
            short x = f2bf(p[jj]);
            a0[jj] = x; lds[j0 + jj][i] = x;
        }
        #pragma unroll
        for (int jj = 0; jj < 8; ++jj) {
            short x = f2bf(p[8 + jj]);
            a1[jj] = x; lds[j0 + 8 + jj][i] = x;
        }
        __hip_bfloat16* adst = Ab + ((size_t)(b * 1024) + n0 + i) * 512 + h * 64 + j0;
        *reinterpret_cast<short8*>(adst)     = a0;
        *reinterpret_cast<short8*>(adst + 8) = a1;
    }
    __syncthreads();
    {
        const int j  = t >> 2;
        const int i0 = (t & 3) * 16;
        __hip_bfloat16* q = Vt + (((size_t)(b * 8 + h) * 64) + j) * 1024 + n0 + i0;
        short8 v0 = *reinterpret_cast<const short8*>(&lds[j][i0]);
        short8 v1 = *reinterpret_cast<const short8*>(&lds[j][i0 + 8]);
        *reinterpret_cast<short8*>(q)     = v0;
        *reinterpret_cast<short8*>(q + 8) = v1;
    }
}

// ---------------------------------------------------------------------------
// Kernel 2: projection GEMM, all-bf16 inputs (unchanged from R6).
// ---------------------------------------------------------------------------
__global__ __launch_bounds__(256, 4) void proj_kernel(
    const __hip_bfloat16* __restrict__ An, const __hip_bfloat16* __restrict__ Ar,
    const __hip_bfloat16* __restrict__ Wtn, const __hip_bfloat16* __restrict__ Wtr,
    const float* __restrict__ bn, const float* __restrict__ br,
    __hip_bfloat16* __restrict__ Qn, __hip_bfloat16* __restrict__ Kn,
    __hip_bfloat16* __restrict__ Qr, __hip_bfloat16* __restrict__ Kr)
{
    const int m0 = blockIdx.x * 64;
    const int c0 = blockIdx.y * 128;
    const int g  = blockIdx.z;
    const __hip_bfloat16* A  = g ? Ar  : An;
    const __hip_bfloat16* Wt = g ? Wtr : Wtn;
    const float* bias = g ? br : bn;
    __hip_bfloat16* Qd = g ? Qr : Qn;
    __hip_bfloat16* Kd = g ? Kr : Kn;

    __shared__ short Bt[2][4][128][8];

    const int t    = threadIdx.x;
    const int lane = t & 63;
    const int w    = t >> 6;
    const int l15  = lane & 15;
    const int lg   = lane >> 4;

    auto stage = [&](int buf, int kk) {
        #pragma unroll
        for (int rep = 0; rep < 2; ++rep) {
            const int u = rep * 256 + t;
            const int s = u >> 7;
            const int c = u & 127;
            const __hip_bfloat16* src = Wt + (size_t)(c0 + c) * 512 + kk + s * 8;
            __builtin_amdgcn_global_load_lds(
                (const __attribute__((address_space(1))) unsigned int*)src,
                (__attribute__((address_space(3))) unsigned int*)&Bt[buf][s][c][0],
                16, 0, 0);
        }
    };

    float4v acc[8] = {};
    const int mrow = m0 + w * 16 + l15;

    stage(0, 0);
    __syncthreads();

    for (int kk = 0; kk < 512; kk += 32) {
        const int buf = (kk >> 5) & 1;
        if (kk < 480) stage(buf ^ 1, kk + 32);
        short8 afrag = *reinterpret_cast<const short8*>(
            A + (size_t)mrow * 512 + kk + lg * 8);
        #pragma unroll
        for (int cs = 0; cs < 8; ++cs) {
            short8 bfrag = *reinterpret_cast<const short8*>(
                &Bt[buf][lg][cs * 16 + l15][0]);
            acc[cs] = MFMA16(afrag, bfrag, acc[cs]);
        }
        __syncthreads();
    }

    #pragma unroll
    for (int cs = 0; cs < 8; ++cs) {
        const int c  = c0 + cs * 16 + l15;
        const bool isK = (c >= 512);
        const int hh = (c >> 6) & 7;
        const int d  = c & 63;
        __hip_bfloat16* dst = isK ? Kd : Qd;
        const float bv = bias[c];
        #pragma unroll
        for (int r = 0; r < 4; ++r) {
            const int m = m0 + w * 16 + lg * 4 + r;
            const int b = m >> 10, n = m & 1023;
            dst[(((size_t)(b * 8 + hh) * 1024 + n) * 64) + d] =
                __float2bfloat16(acc[cs][r] + bv);
        }
    }
}

// ---------------------------------------------------------------------------
// Kernel 3: attention, softmax over HEADS.  R9 = R8 + manual MFMA hazard
// wait-states around the inline-asm PV MFMAs (the hazard recognizer cannot
// see inside INLINEASM: VALU-write->MFMA-read SrcA needs 2 states; MFMA-
// write->VALU-read needs nops before the epilogue).
// grid: (16 combos, 32 ntiles of 32 rows) = 512 blocks, XCD-local, 2/CU.
// block 512 (8 waves = 4 hg head-pairs x 2 iw n-subtiles).
// Per iter: kf ds_reads -> stage next-K DMA (dbuf) -> QK^T -> exp in-reg ->
// partial sums via ds atomicAdd into 3-slot-rotated X -> V b64 loads ->
// ONE barrier -> rcp -> P packed in registers -> PV via 16x16x16 MFMA asm.
// LDS 76KB = K dbuf 64 + X 12.
// ---------------------------------------------------------------------------
__global__ __launch_bounds__(512, 4) void attn_kernel(
    const __hip_bfloat16* __restrict__ Qn, const __hip_bfloat16* __restrict__ Kn,
    const __hip_bfloat16* __restrict__ Qr, const __hip_bfloat16* __restrict__ Kr,
    const __hip_bfloat16* __restrict__ Vtn, const __hip_bfloat16* __restrict__ Vtr,
    float* __restrict__ out)
{
    const int combo = blockIdx.x;
    const int bb    = combo & 7;
    const int dir   = combo >> 3;
    const int nt    = blockIdx.y;     // 0..31
    const __hip_bfloat16* Q  = dir ? Qr  : Qn;
    const __hip_bfloat16* K  = dir ? Kn  : Kr;
    const __hip_bfloat16* Vt = dir ? Vtn : Vtr;
    float* O = out + (size_t)dir * (8u * 1024u * 512u);

    const int t    = threadIdx.x;
    const int lane = t & 63;
    const int w    = t >> 6;
    const int iw   = w & 1;
    const int hg   = w >> 1;          // head pair 0..3
    const int h0   = hg * 2;
    const int l15  = lane & 15;
    const int lg   = lane >> 4;

    __shared__ short K_s[2][8 * 32 * 64]; // 64KB dbuf [h][m][d] slot-swizzled
    __shared__ float X_s[3][2][512];      // 12KB 3-slot rotated [par][iw][p*64+lane]

    const int n0 = nt * 32;
    const float C = 0.125f * 1.44269504f;

    const __hip_bfloat16* Vb[2] = {
        Vt + (size_t)((bb * 8 + h0)     * 64) * 1024,
        Vt + (size_t)((bb * 8 + h0 + 1) * 64) * 1024 };

    auto stage = [&](int bufn, int mt) {
        #pragma unroll
        for (int i = 0; i < 4; ++i) {
            const int u    = (w * 4 + i) * 64 + lane;
            const int h    = u >> 8;
            const int mr   = (u >> 3) & 31;
            const int slot = (u & 7) ^ (mr & 7);
            const __hip_bfloat16* g =
                K + ((size_t)((bb * 8 + h) * 1024) + mt + mr) * 64 + slot * 8;
            __builtin_amdgcn_global_load_lds(
                (const __attribute__((address_space(1))) unsigned int*)g,
                (__attribute__((address_space(3))) unsigned int*)&K_s[bufn][u * 8],
                16, 0, 0);
        }
    };

    // Q fragments (B operand of QK^T): qf[hh][kc]
    short8 qf[2][2];
    #pragma unroll
    for (int hh = 0; hh < 2; ++hh)
        #pragma unroll
        for (int kc = 0; kc < 2; ++kc)
            qf[hh][kc] = *reinterpret_cast<const short8*>(
                Q + ((size_t)((bb * 8 + h0 + hh) * 1024) + n0 + iw * 16 + l15) * 64
                  + kc * 32 + lg * 8);

    float4v oacc[2][4] = {};              // [hh][dd]

    // prologue: zero X, stage first K tile
    {
        float* xf = &X_s[0][0][0];
        #pragma unroll
        for (int z = 0; z < 6; ++z) xf[t + z * 512] = 0.f;
    }
    stage(0, 0);
    __syncthreads();

    for (int it = 0; it < 32; ++it) {
        const int m0  = it << 5;
        const int buf = it & 1;
        const int par = it % 3;
        // ---- K frags from staged LDS (swizzled slots) ----
        short8 kf[2][2][2];               // [hh][j][kc]
        const short* ks = K_s[buf];
        #pragma unroll
        for (int hh = 0; hh < 2; ++hh)
            #pragma unroll
            for (int j = 0; j < 2; ++j) {
                const int mr = j * 16 + l15;
                #pragma unroll
                for (int kc = 0; kc < 2; ++kc)
                    kf[hh][j][kc] = *reinterpret_cast<const short8*>(
                        ks + (h0 + hh) * 2048 + mr * 64
                           + (((kc * 4 + lg) ^ (mr & 7)) * 8));
            }
        // ---- stage next iter's K (drains at the single barrier below) ----
        stage(buf ^ 1, (it < 31) ? m0 + 32 : 0);
        // ---- S^T = K Q^T ----
        float4v sacc[2][2];               // [hh][j]
        __builtin_amdgcn_s_setprio(1);
        #pragma unroll
        for (int hh = 0; hh < 2; ++hh)
            #pragma unroll
            for (int j = 0; j < 2; ++j) {
                float4v s = {};
                s = MFMA16(kf[hh][j][0], qf[hh][0], s);
                s = MFMA16(kf[hh][j][1], qf[hh][1], s);
                sacc[hh][j] = s;
            }
        __builtin_amdgcn_s_setprio(0);
        // ---- exp in-register; head-pair partial sums -> LDS atomic add ----
        float e[2][8];
        float ps[8];
        #pragma unroll
        for (int j = 0; j < 2; ++j)
            #pragma unroll
            for (int r = 0; r < 4; ++r) {
                float e0 = exp2f(sacc[0][j][r] * C);
                float e1 = exp2f(sacc[1][j][r] * C);
                e[0][j * 4 + r] = e0;
                e[1][j * 4 + r] = e1;
                ps[j * 4 + r] = e0 + e1;
            }
        #pragma unroll
        for (int p = 0; p < 8; ++p)
            atomicAdd(&X_s[par][iw][p * 64 + lane], ps[p]);
        // ---- V fragments for PV (K=16 layout: 4 consecutive m) ----
        short4v vf[2][4][2];              // [hh][dd][j]
        #pragma unroll
        for (int hh = 0; hh < 2; ++hh)
            #pragma unroll
            for (int dd = 0; dd < 4; ++dd)
                #pragma unroll
                for (int j = 0; j < 2; ++j)
                    vf[hh][dd][j] = *reinterpret_cast<const short4v*>(
                        Vb[hh] + (size_t)(dd * 16 + l15) * 1024
                               + m0 + j * 16 + lg * 4);
        __syncthreads();   // THE barrier: X sums complete, K DMA drained
        // ---- totals + rcp ----
        float inv8[8];
        #pragma unroll
        for (int p = 0; p < 8; ++p)
            inv8[p] = __builtin_amdgcn_rcpf(X_s[par][iw][p * 64 + lane]);
        // ---- zero the slot read last iter (barrier-separated both sides) ----
        if (hg == 0) {
            const int zs = (par + 2) % 3;
            #pragma unroll
            for (int p = 0; p < 8; ++p)
                X_s[zs][iw][p * 64 + lane] = 0.f;
        }
        // ---- P in registers -> PV via 16x16x16 MFMA (manual hazard nops:
        //      s_nop 3 covers VALU-write(pf)->MFMA-read-SrcA/C; the 4 MFMAs
        //      within a block have disjoint D/SrcC (0 states); cross-block
        //      SrcC accumulation forwards with 0 states) ----
        __builtin_amdgcn_s_setprio(1);
        #pragma unroll
        for (int hh = 0; hh < 2; ++hh) {
            #pragma unroll
            for (int j = 0; j < 2; ++j) {
                short4v pf;
                #pragma unroll
                for (int r = 0; r < 4; ++r)
                    pf[r] = f2bf(e[hh][j * 4 + r] * inv8[j * 4 + r]);
                asm("s_nop 3\n\t"
                    "v_mfma_f32_16x16x16_bf16 %0, %4, %5, %0\n\t"
                    "v_mfma_f32_16x16x16_bf16 %1, %4, %6, %1\n\t"
                    "v_mfma_f32_16x16x16_bf16 %2, %4, %7, %2\n\t"
                    "v_mfma_f32_16x16x16_bf16 %3, %4, %8, %3"
                    : "+v"(oacc[hh][0]), "+v"(oacc[hh][1]),
                      "+v"(oacc[hh][2]), "+v"(oacc[hh][3])
                    : "v"(pf), "v"(vf[hh][0][j]), "v"(vf[hh][1][j]),
                      "v"(vf[hh][2][j]), "v"(vf[hh][3][j]));
            }
        }
        __builtin_amdgcn_s_setprio(0);
    }

    // ---- drain MFMA-write -> VALU-read hazard before the epilogue ----
    asm volatile("s_nop 7\n\ts_nop 7"
        : "+v"(oacc[0][0]), "+v"(oacc[0][1]), "+v"(oacc[0][2]), "+v"(oacc[0][3]),
          "+v"(oacc[1][0]), "+v"(oacc[1][1]), "+v"(oacc[1][2]), "+v"(oacc[1][3]));

    // ---- epilogue: O[b][n][h*64+d] f32 ----
    #pragma unroll
    for (int hh = 0; hh < 2; ++hh)
        #pragma unroll
        for (int dd = 0; dd < 4; ++dd)
            #pragma unroll
            for (int r = 0; r < 4; ++r) {
                const int n = n0 + iw * 16 + lg * 4 + r;
                const int d = dd * 16 + l15;
                O[((size_t)(bb * 1024) + n) * 512 + (h0 + hh) * 64 + d] =
                    oacc[hh][dd][r];
            }
}

extern "C" void kernel_launch(void* const* d_in, const int* in_sizes, int n_in,
                              void* d_out, int out_size, void* d_ws, size_t ws_size,
                              hipStream_t stream) {
    const float* nv = (const float*)d_in[0];
    const float* rv = (const float*)d_in[1];
    const float* Wn = (const float*)d_in[2];
    const float* bn = (const float*)d_in[3];
    const float* Wr = (const float*)d_in[4];
    const float* br = (const float*)d_in[5];
    float* out = (float*)d_out;

    __hip_bfloat16* w = (__hip_bfloat16*)d_ws;
    const size_t E = 8ull * 8 * 1024 * 64;    // 4M elems
    __hip_bfloat16* Qn  = w;
    __hip_bfloat16* Kn  = w + E;
    __hip_bfloat16* Qr  = w + 2 * E;
    __hip_bfloat16* Kr  = w + 3 * E;
    __hip_bfloat16* Vtn = w + 4 * E;
    __hip_bfloat16* Vtr = w + 5 * E;
    __hip_bfloat16* An  = w + 6 * E;
    __hip_bfloat16* Ar  = w + 7 * E;
    __hip_bfloat16* Wtn = w + 8 * E;
    __hip_bfloat16* Wtr = w + 8 * E + 512 * 1024;

    wt_kernel  <<<dim3(16, 8, 2), 256, 0, stream>>>(Wn, Wr, Wtn, Wtr);
    prep_kernel<<<dim3(32, 8, 8), 256, 0, stream>>>(nv, rv, Vtn, Vtr, An, Ar);
    proj_kernel<<<dim3(128, 8, 2), 256, 0, stream>>>(An, Ar, Wtn, Wtr, bn, br,
                                                     Qn, Kn, Qr, Kr);
    attn_kernel<<<dim3(16, 32), 512, 0, stream>>>(Qn, Kn, Qr, Kr, Vtn, Vtr, out);
}

// Round 10
// 172.113 us; speedup vs baseline: 2.6884x; 2.6884x over previous
//
#include <hip/hip_runtime.h>
#include <hip/hip_bf16.h>

typedef __attribute__((ext_vector_type(8))) short short8;
typedef __attribute__((ext_vector_type(4))) short short4v;
typedef __attribute__((ext_vector_type(4))) float float4v;

#define MFMA16(a, b, c) __builtin_amdgcn_mfma_f32_16x16x32_bf16(a, b, c, 0, 0, 0)

__device__ __forceinline__ short f2bf(float f) {
    __hip_bfloat16 hb = __float2bfloat16(f);
    return *reinterpret_cast<short*>(&hb);
}

// ---------------------------------------------------------------------------
// Kernel 0: W transpose+convert.  W[512][1024] f32 -> Wt[1024][512] bf16.
// ---------------------------------------------------------------------------
__global__ __launch_bounds__(256) void wt_kernel(
    const float* __restrict__ Wn, const float* __restrict__ Wr,
    __hip_bfloat16* __restrict__ Wtn, __hip_bfloat16* __restrict__ Wtr)
{
    const int c0 = blockIdx.x * 64;
    const int k0 = blockIdx.y * 64;
    const int g  = blockIdx.z;
    const float* W = g ? Wr : Wn;
    __hip_bfloat16* Wt = g ? Wtr : Wtn;

    __shared__ short lds[64][72];
    const int t = threadIdx.x;
    {
        const int i  = t >> 2;
        const int j0 = (t & 3) * 16;
        const float* p = W + (size_t)(k0 + i) * 1024 + c0 + j0;
        #pragma unroll
        for (int jj = 0; jj < 16; ++jj)
            lds[j0 + jj][i] = f2bf(p[jj]);
    }
    __syncthreads();
    {
        const int j  = t >> 2;
        const int i0 = (t & 3) * 16;
        __hip_bfloat16* q = Wt + (size_t)(c0 + j) * 512 + k0 + i0;
        short8 v0 = *reinterpret_cast<const short8*>(&lds[j][i0]);
        short8 v1 = *reinterpret_cast<const short8*>(&lds[j][i0 + 8]);
        *reinterpret_cast<short8*>(q)     = v0;
        *reinterpret_cast<short8*>(q + 8) = v1;
    }
}

// ---------------------------------------------------------------------------
// Kernel 1: prep.  nv/rv f32 -> Vt [b][h][64][1024] bf16 + Abf [b][n][512] bf16
// ---------------------------------------------------------------------------
__global__ __launch_bounds__(256) void prep_kernel(
    const float* __restrict__ nv, const float* __restrict__ rv,
    __hip_bfloat16* __restrict__ Vtn, __hip_bfloat16* __restrict__ Vtr,
    __hip_bfloat16* __restrict__ An,  __hip_bfloat16* __restrict__ Ar)
{
    const int ntile = blockIdx.x & 15;
    const int src   = blockIdx.x >> 4;
    const int h     = blockIdx.y;
    const int b     = blockIdx.z;
    const float* V  = src ? rv : nv;
    __hip_bfloat16* Vt = src ? Vtr : Vtn;
    __hip_bfloat16* Ab = src ? Ar  : An;

    __shared__ short lds[64][72];
    const int t  = threadIdx.x;
    const int n0 = ntile * 64;
    {
        const int i  = t >> 2;
        const int j0 = (t & 3) * 16;
        const float* p = V + ((size_t)(b * 1024) + n0 + i) * 512 + h * 64 + j0;
        short8 a0, a1;
        #pragma unroll
        for (int jj = 0; jj < 8; ++jj) {
            short x = f2bf(p[jj]);
            a0[jj] = x; lds[j0 + jj][i] = x;
        }
        #pragma unroll
        for (int jj = 0; jj < 8; ++jj) {
            short x = f2bf(p[8 + jj]);
            a1[jj] = x; lds[j0 + 8 + jj][i] = x;
        }
        __hip_bfloat16* adst = Ab + ((size_t)(b * 1024) + n0 + i) * 512 + h * 64 + j0;
        *reinterpret_cast<short8*>(adst)     = a0;
        *reinterpret_cast<short8*>(adst + 8) = a1;
    }
    __syncthreads();
    {
        const int j  = t >> 2;
        const int i0 = (t & 3) * 16;
        __hip_bfloat16* q = Vt + (((size_t)(b * 8 + h) * 64) + j) * 1024 + n0 + i0;
        short8 v0 = *reinterpret_cast<const short8*>(&lds[j][i0]);
        short8 v1 = *reinterpret_cast<const short8*>(&lds[j][i0 + 8]);
        *reinterpret_cast<short8*>(q)     = v0;
        *reinterpret_cast<short8*>(q + 8) = v1;
    }
}

// ---------------------------------------------------------------------------
// Kernel 2: projection GEMM, all-bf16 inputs.  R10: 64m x 256c tile so A is
// re-read only 4x across c-tiles (67 -> 34 MB).  Wt panel staged via
// global_load_lds (slot-major, linear dest), double-buffered, 1 barrier/iter.
// grid: (128 mtiles, 4 ctiles, 2 gemms), block 256 (4 waves).
// ---------------------------------------------------------------------------
__global__ __launch_bounds__(256, 4) void proj_kernel(
    const __hip_bfloat16* __restrict__ An, const __hip_bfloat16* __restrict__ Ar,
    const __hip_bfloat16* __restrict__ Wtn, const __hip_bfloat16* __restrict__ Wtr,
    const float* __restrict__ bn, const float* __restrict__ br,
    __hip_bfloat16* __restrict__ Qn, __hip_bfloat16* __restrict__ Kn,
    __hip_bfloat16* __restrict__ Qr, __hip_bfloat16* __restrict__ Kr)
{
    const int m0 = blockIdx.x * 64;
    const int c0 = blockIdx.y * 256;
    const int g  = blockIdx.z;
    const __hip_bfloat16* A  = g ? Ar  : An;
    const __hip_bfloat16* Wt = g ? Wtr : Wtn;
    const float* bias = g ? br : bn;
    __hip_bfloat16* Qd = g ? Qr : Qn;
    __hip_bfloat16* Kd = g ? Kr : Kn;

    __shared__ short Bt[2][4][256][8];   // [buf][k-slot][c][8 bf16] = 32KB

    const int t    = threadIdx.x;
    const int lane = t & 63;
    const int w    = t >> 6;
    const int l15  = lane & 15;
    const int lg   = lane >> 4;

    auto stage = [&](int buf, int kk) {
        #pragma unroll
        for (int rep = 0; rep < 4; ++rep) {
            const int u = rep * 256 + t;        // 16B unit 0..1023
            const int s = u >> 8;               // k-slot 0..3
            const int c = u & 255;
            const __hip_bfloat16* src = Wt + (size_t)(c0 + c) * 512 + kk + s * 8;
            __builtin_amdgcn_global_load_lds(
                (const __attribute__((address_space(1))) unsigned int*)src,
                (__attribute__((address_space(3))) unsigned int*)&Bt[buf][s][c][0],
                16, 0, 0);
        }
    };

    float4v acc[16] = {};
    const int mrow = m0 + w * 16 + l15;

    stage(0, 0);
    __syncthreads();

    for (int kk = 0; kk < 512; kk += 32) {
        const int buf = (kk >> 5) & 1;
        if (kk < 480) stage(buf ^ 1, kk + 32);
        short8 afrag = *reinterpret_cast<const short8*>(
            A + (size_t)mrow * 512 + kk + lg * 8);
        #pragma unroll
        for (int cs = 0; cs < 16; ++cs) {
            short8 bfrag = *reinterpret_cast<const short8*>(
                &Bt[buf][lg][cs * 16 + l15][0]);
            acc[cs] = MFMA16(afrag, bfrag, acc[cs]);
        }
        __syncthreads();
    }

    #pragma unroll
    for (int cs = 0; cs < 16; ++cs) {
        const int c  = c0 + cs * 16 + l15;
        const bool isK = (c >= 512);
        const int hh = (c >> 6) & 7;
        const int d  = c & 63;
        __hip_bfloat16* dst = isK ? Kd : Qd;
        const float bv = bias[c];
        #pragma unroll
        for (int r = 0; r < 4; ++r) {
            const int m = m0 + w * 16 + lg * 4 + r;
            const int b = m >> 10, n = m & 1023;
            dst[(((size_t)(b * 8 + hh) * 1024 + n) * 64) + d] =
                __float2bfloat16(acc[cs][r] + bv);
        }
    }
}

// ---------------------------------------------------------------------------
// Kernel 3: attention, softmax over HEADS.  R5's kernel restored VERBATIM
// (measured: 120us, MfmaUtil 11.5%, VALUBusy 44%, FETCH ~25MB).
// grid: (16 combos = b + 8*dir, 16 ntiles of 64 rows) -> 256 blocks, 1/CU,
// XCD-local (id%8 == combo%8). block 512 (8 waves: hg head-pair x iw).
// K tile (8 heads x 32m x 64d = 32KB) DMA-staged, double-buffered, slot-XOR
// swizzled (swizzle on global source, linear LDS dest). V frags register
// loads at iter top. Scalar X exchange. Stage issued after ns0's barrier.
// ---------------------------------------------------------------------------
__global__ __launch_bounds__(512, 2) void attn_kernel(
    const __hip_bfloat16* __restrict__ Qn, const __hip_bfloat16* __restrict__ Kn,
    const __hip_bfloat16* __restrict__ Qr, const __hip_bfloat16* __restrict__ Kr,
    const __hip_bfloat16* __restrict__ Vtn, const __hip_bfloat16* __restrict__ Vtr,
    float* __restrict__ out)
{
    const int combo = blockIdx.x;     // 0..15
    const int bb    = combo & 7;
    const int dir   = combo >> 3;
    const int nt    = blockIdx.y;     // 0..15
    const __hip_bfloat16* Q  = dir ? Qr  : Qn;
    const __hip_bfloat16* K  = dir ? Kn  : Kr;
    const __hip_bfloat16* Vt = dir ? Vtn : Vtr;
    float* O = out + (size_t)dir * (8u * 1024u * 512u);

    const int t    = threadIdx.x;
    const int lane = t & 63;
    const int w    = t >> 6;          // 0..7
    const int iw   = w & 1;           // n-subtile within pair
    const int hg   = w >> 1;          // head pair 0..3
    const int h0   = hg * 2;
    const int l15  = lane & 15;
    const int lg   = lane >> 4;       // 0..3

    __shared__ short K_s[2][8 * 32 * 64];   // 64KB: [buf][h][m][d] (slot-swizzled)
    __shared__ short P_s[8][32][40];        // 20KB, wave-private regions
    __shared__ float X_s[2][4][2][512];     // 16KB [ns][hg][iw][p*64+lane]

    const int n0 = nt * 64;
    const float C = 0.125f * 1.44269504f;   // SCALE * log2(e)

    const __hip_bfloat16* Vb[2] = {
        Vt + (size_t)((bb * 8 + h0)     * 64) * 1024,
        Vt + (size_t)((bb * 8 + h0 + 1) * 64) * 1024 };

    auto stage = [&](int bufn, int mt) {
        #pragma unroll
        for (int i = 0; i < 4; ++i) {
            const int u    = (w * 4 + i) * 64 + lane;   // 16B unit, 0..2047
            const int h    = u >> 8;                    // 256 units per head
            const int mr   = (u >> 3) & 31;             // row within tile
            const int slot = (u & 7) ^ (mr & 7);        // swizzled 16B slot
            const __hip_bfloat16* g =
                K + ((size_t)((bb * 8 + h) * 1024) + mt + mr) * 64 + slot * 8;
            __builtin_amdgcn_global_load_lds(
                (const __attribute__((address_space(1))) unsigned int*)g,
                (__attribute__((address_space(3))) unsigned int*)&K_s[bufn][u * 8],
                16, 0, 0);
        }
    };

    // Q fragments (B operand): qf[ns][hh][kc]
    short8 qf[2][2][2];
    #pragma unroll
    for (int ns = 0; ns < 2; ++ns)
        #pragma unroll
        for (int hh = 0; hh < 2; ++hh)
            #pragma unroll
            for (int kc = 0; kc < 2; ++kc)
                qf[ns][hh][kc] = *reinterpret_cast<const short8*>(
                    Q + ((size_t)((bb * 8 + h0 + hh) * 1024) + n0 + ns * 32 + iw * 16 + l15) * 64
                      + kc * 32 + lg * 8);

    float4v oacc[2][2][4] = {};       // [ns][hh][dd]

    stage(0, 0);
    __syncthreads();                  // drain prologue staging

    for (int it = 0; it < 32; ++it) {
        const int m0  = it << 5;
        const int buf = it & 1;
        // ---- V frags: issue early (global, consumed at PV) ----
        short8 vf[2][4];              // [hh][dd]
        #pragma unroll
        for (int hh = 0; hh < 2; ++hh)
            #pragma unroll
            for (int dd = 0; dd < 4; ++dd)
                vf[hh][dd] = *reinterpret_cast<const short8*>(
                    Vb[hh] + (size_t)(dd * 16 + l15) * 1024 + m0 + lg * 8);
        // ---- K frags from staged LDS (swizzled slots) ----
        short8 kf[2][2][2];           // [hh][j][kc]
        const short* ks = K_s[buf];
        #pragma unroll
        for (int hh = 0; hh < 2; ++hh)
            #pragma unroll
            for (int j = 0; j < 2; ++j) {
                const int mr = j * 16 + l15;
                #pragma unroll
                for (int kc = 0; kc < 2; ++kc)
                    kf[hh][j][kc] = *reinterpret_cast<const short8*>(
                        ks + (h0 + hh) * 2048 + mr * 64
                           + (((kc * 4 + lg) ^ (mr & 7)) * 8));
            }

        #pragma unroll
        for (int ns = 0; ns < 2; ++ns) {
            // ---- S^T = K Q^T, exp in-register ----
            float4v sacc[2][2] = {};  // [hh][j]
            #pragma unroll
            for (int hh = 0; hh < 2; ++hh)
                #pragma unroll
                for (int j = 0; j < 2; ++j)
                    #pragma unroll
                    for (int kc = 0; kc < 2; ++kc)
                        sacc[hh][j] = MFMA16(kf[hh][j][kc], qf[ns][hh][kc], sacc[hh][j]);
            float e[2][8];
            float ps[8] = {0.f, 0.f, 0.f, 0.f, 0.f, 0.f, 0.f, 0.f};
            #pragma unroll
            for (int hh = 0; hh < 2; ++hh)
                #pragma unroll
                for (int j = 0; j < 2; ++j)
                    #pragma unroll
                    for (int r = 0; r < 4; ++r) {
                        float ev = exp2f(sacc[hh][j][r] * C);
                        e[hh][j * 4 + r] = ev;
                        ps[j * 4 + r] += ev;
                    }
            // ---- exchange head-partial sums (scalar, conflict-free) ----
            #pragma unroll
            for (int p = 0; p < 8; ++p)
                X_s[ns][hg][iw][p * 64 + lane] = ps[p];
            __syncthreads();
            if (ns == 0)   // stage next iter's K; drains at end-of-iter barrier
                stage(buf ^ 1, (it < 31) ? m0 + 32 : 0);
            float inv[8];
            #pragma unroll
            for (int p = 0; p < 8; ++p) {
                float tot = ps[p];
                #pragma unroll
                for (int g = 1; g < 4; ++g)
                    tot += X_s[ns][(hg + g) & 3][iw][p * 64 + lane];
                inv[p] = __builtin_amdgcn_rcpf(tot);
            }
            // ---- P = e * inv -> wave-private P_s (b64 packed) ----
            #pragma unroll
            for (int hh = 0; hh < 2; ++hh)
                #pragma unroll
                for (int j = 0; j < 2; ++j) {
                    short4v pk;
                    #pragma unroll
                    for (int r = 0; r < 4; ++r)
                        pk[r] = f2bf(e[hh][j * 4 + r] * inv[j * 4 + r]);
                    *reinterpret_cast<short4v*>(
                        &P_s[h0 + hh][iw * 16 + l15][j * 16 + lg * 4]) = pk;
                }
            // ---- O += P V (P_s wave-private: in-wave LDS ordering suffices) ----
            #pragma unroll
            for (int hh = 0; hh < 2; ++hh) {
                short8 pf = *reinterpret_cast<const short8*>(
                    &P_s[h0 + hh][iw * 16 + l15][lg * 8]);
                #pragma unroll
                for (int dd = 0; dd < 4; ++dd)
                    oacc[ns][hh][dd] = MFMA16(pf, vf[hh][dd], oacc[ns][hh][dd]);
            }
        }
        __syncthreads();              // fences X slots + drains staging DMA
    }

    // ---- epilogue: O[b][n][h*64+d] f32 ----
    #pragma unroll
    for (int ns = 0; ns < 2; ++ns)
        #pragma unroll
        for (int hh = 0; hh < 2; ++hh)
            #pragma unroll
            for (int dd = 0; dd < 4; ++dd)
                #pragma unroll
                for (int r = 0; r < 4; ++r) {
                    const int n = n0 + ns * 32 + iw * 16 + lg * 4 + r;
                    const int d = dd * 16 + l15;
                    O[((size_t)(bb * 1024) + n) * 512 + (h0 + hh) * 64 + d] =
                        oacc[ns][hh][dd][r];
                }
}

extern "C" void kernel_launch(void* const* d_in, const int* in_sizes, int n_in,
                              void* d_out, int out_size, void* d_ws, size_t ws_size,
                              hipStream_t stream) {
    const float* nv = (const float*)d_in[0];
    const float* rv = (const float*)d_in[1];
    const float* Wn = (const float*)d_in[2];
    const float* bn = (const float*)d_in[3];
    const float* Wr = (const float*)d_in[4];
    const float* br = (const float*)d_in[5];
    float* out = (float*)d_out;

    __hip_bfloat16* w = (__hip_bfloat16*)d_ws;
    const size_t E = 8ull * 8 * 1024 * 64;    // 4M elems
    __hip_bfloat16* Qn  = w;
    __hip_bfloat16* Kn  = w + E;
    __hip_bfloat16* Qr  = w + 2 * E;
    __hip_bfloat16* Kr  = w + 3 * E;
    __hip_bfloat16* Vtn = w + 4 * E;
    __hip_bfloat16* Vtr = w + 5 * E;
    __hip_bfloat16* An  = w + 6 * E;
    __hip_bfloat16* Ar  = w + 7 * E;
    __hip_bfloat16* Wtn = w + 8 * E;
    __hip_bfloat16* Wtr = w + 8 * E + 512 * 1024;

    wt_kernel  <<<dim3(16, 8, 2), 256, 0, stream>>>(Wn, Wr, Wtn, Wtr);
    prep_kernel<<<dim3(32, 8, 8), 256, 0, stream>>>(nv, rv, Vtn, Vtr, An, Ar);
    proj_kernel<<<dim3(128, 4, 2), 256, 0, stream>>>(An, Ar, Wtn, Wtr, bn, br,
                                                     Qn, Kn, Qr, Kr);
    attn_kernel<<<dim3(16, 16), 512, 0, stream>>>(Qn, Kn, Qr, Kr, Vtn, Vtr, out);
}

// Round 11
// 170.159 us; speedup vs baseline: 2.7193x; 1.0115x over previous
//
#include <hip/hip_runtime.h>
#include <hip/hip_bf16.h>

typedef __attribute__((ext_vector_type(8))) short short8;
typedef __attribute__((ext_vector_type(4))) short short4v;
typedef __attribute__((ext_vector_type(4))) float float4v;

#define MFMA16(a, b, c) __builtin_amdgcn_mfma_f32_16x16x32_bf16(a, b, c, 0, 0, 0)

__device__ __forceinline__ short f2bf(float f) {
    __hip_bfloat16 hb = __float2bfloat16(f);
    return *reinterpret_cast<short*>(&hb);
}

// ---------------------------------------------------------------------------
// Kernel 1: prep (+ fused wt).  z<8: nv/rv f32 -> Vt [b][h][64][1024] bf16 and
// Abf [b][n][512] bf16.  z==8: W[512][1024] f32 -> Wt[1024][512] bf16.
// grid: (32, 8, 9), block 256.
// ---------------------------------------------------------------------------
__global__ __launch_bounds__(256) void prep_kernel(
    const float* __restrict__ nv, const float* __restrict__ rv,
    const float* __restrict__ Wn, const float* __restrict__ Wr,
    __hip_bfloat16* __restrict__ Vtn, __hip_bfloat16* __restrict__ Vtr,
    __hip_bfloat16* __restrict__ An,  __hip_bfloat16* __restrict__ Ar,
    __hip_bfloat16* __restrict__ Wtn, __hip_bfloat16* __restrict__ Wtr)
{
    __shared__ short lds[64][72];
    const int t = threadIdx.x;

    if (blockIdx.z == 8) {
        // ---- wt part: 256 blocks = 16 ctiles x 8 ktiles x 2 gemms ----
        const int id = blockIdx.x + 32 * blockIdx.y;   // 0..255
        const int c0 = (id & 15) * 64;
        const int k0 = ((id >> 4) & 7) * 64;
        const int g  = id >> 7;
        const float* W = g ? Wr : Wn;
        __hip_bfloat16* Wt = g ? Wtr : Wtn;
        {
            const int i  = t >> 2;            // k row
            const int j0 = (t & 3) * 16;      // c chunk
            const float* p = W + (size_t)(k0 + i) * 1024 + c0 + j0;
            #pragma unroll
            for (int jj = 0; jj < 16; ++jj)
                lds[j0 + jj][i] = f2bf(p[jj]);  // lds[c][k]
        }
        __syncthreads();
        {
            const int j  = t >> 2;            // c row
            const int i0 = (t & 3) * 16;      // k chunk
            __hip_bfloat16* q = Wt + (size_t)(c0 + j) * 512 + k0 + i0;
            short8 v0 = *reinterpret_cast<const short8*>(&lds[j][i0]);
            short8 v1 = *reinterpret_cast<const short8*>(&lds[j][i0 + 8]);
            *reinterpret_cast<short8*>(q)     = v0;
            *reinterpret_cast<short8*>(q + 8) = v1;
        }
        return;
    }

    // ---- prep part ----
    const int ntile = blockIdx.x & 15;
    const int src   = blockIdx.x >> 4;
    const int h     = blockIdx.y;
    const int b     = blockIdx.z;
    const float* V  = src ? rv : nv;
    __hip_bfloat16* Vt = src ? Vtr : Vtn;
    __hip_bfloat16* Ab = src ? Ar  : An;

    const int n0 = ntile * 64;
    {
        const int i  = t >> 2;
        const int j0 = (t & 3) * 16;
        const float* p = V + ((size_t)(b * 1024) + n0 + i) * 512 + h * 64 + j0;
        short8 a0, a1;
        #pragma unroll
        for (int jj = 0; jj < 8; ++jj) {
            short x = f2bf(p[jj]);
            a0[jj] = x; lds[j0 + jj][i] = x;
        }
        #pragma unroll
        for (int jj = 0; jj < 8; ++jj) {
            short x = f2bf(p[8 + jj]);
            a1[jj] = x; lds[j0 + 8 + jj][i] = x;
        }
        __hip_bfloat16* adst = Ab + ((size_t)(b * 1024) + n0 + i) * 512 + h * 64 + j0;
        *reinterpret_cast<short8*>(adst)     = a0;
        *reinterpret_cast<short8*>(adst + 8) = a1;
    }
    __syncthreads();
    {
        const int j  = t >> 2;
        const int i0 = (t & 3) * 16;
        __hip_bfloat16* q = Vt + (((size_t)(b * 8 + h) * 64) + j) * 1024 + n0 + i0;
        short8 v0 = *reinterpret_cast<const short8*>(&lds[j][i0]);
        short8 v1 = *reinterpret_cast<const short8*>(&lds[j][i0 + 8]);
        *reinterpret_cast<short8*>(q)     = v0;
        *reinterpret_cast<short8*>(q + 8) = v1;
    }
}

// ---------------------------------------------------------------------------
// Kernel 2: projection GEMM, all-bf16 inputs.  64m x 256c tile.
// grid: (128 mtiles, 4 ctiles, 2 gemms), block 256 (4 waves).
// ---------------------------------------------------------------------------
__global__ __launch_bounds__(256, 4) void proj_kernel(
    const __hip_bfloat16* __restrict__ An, const __hip_bfloat16* __restrict__ Ar,
    const __hip_bfloat16* __restrict__ Wtn, const __hip_bfloat16* __restrict__ Wtr,
    const float* __restrict__ bn, const float* __restrict__ br,
    __hip_bfloat16* __restrict__ Qn, __hip_bfloat16* __restrict__ Kn,
    __hip_bfloat16* __restrict__ Qr, __hip_bfloat16* __restrict__ Kr)
{
    const int m0 = blockIdx.x * 64;
    const int c0 = blockIdx.y * 256;
    const int g  = blockIdx.z;
    const __hip_bfloat16* A  = g ? Ar  : An;
    const __hip_bfloat16* Wt = g ? Wtr : Wtn;
    const float* bias = g ? br : bn;
    __hip_bfloat16* Qd = g ? Qr : Qn;
    __hip_bfloat16* Kd = g ? Kr : Kn;

    __shared__ short Bt[2][4][256][8];   // [buf][k-slot][c][8 bf16] = 32KB

    const int t    = threadIdx.x;
    const int lane = t & 63;
    const int w    = t >> 6;
    const int l15  = lane & 15;
    const int lg   = lane >> 4;

    auto stage = [&](int buf, int kk) {
        #pragma unroll
        for (int rep = 0; rep < 4; ++rep) {
            const int u = rep * 256 + t;        // 16B unit 0..1023
            const int s = u >> 8;               // k-slot 0..3
            const int c = u & 255;
            const __hip_bfloat16* src = Wt + (size_t)(c0 + c) * 512 + kk + s * 8;
            __builtin_amdgcn_global_load_lds(
                (const __attribute__((address_space(1))) unsigned int*)src,
                (__attribute__((address_space(3))) unsigned int*)&Bt[buf][s][c][0],
                16, 0, 0);
        }
    };

    float4v acc[16] = {};
    const int mrow = m0 + w * 16 + l15;

    stage(0, 0);
    __syncthreads();

    for (int kk = 0; kk < 512; kk += 32) {
        const int buf = (kk >> 5) & 1;
        if (kk < 480) stage(buf ^ 1, kk + 32);
        short8 afrag = *reinterpret_cast<const short8*>(
            A + (size_t)mrow * 512 + kk + lg * 8);
        #pragma unroll
        for (int cs = 0; cs < 16; ++cs) {
            short8 bfrag = *reinterpret_cast<const short8*>(
                &Bt[buf][lg][cs * 16 + l15][0]);
            acc[cs] = MFMA16(afrag, bfrag, acc[cs]);
        }
        __syncthreads();
    }

    #pragma unroll
    for (int cs = 0; cs < 16; ++cs) {
        const int c  = c0 + cs * 16 + l15;
        const bool isK = (c >= 512);
        const int hh = (c >> 6) & 7;
        const int d  = c & 63;
        __hip_bfloat16* dst = isK ? Kd : Qd;
        const float bv = bias[c];
        #pragma unroll
        for (int r = 0; r < 4; ++r) {
            const int m = m0 + w * 16 + lg * 4 + r;
            const int b = m >> 10, n = m & 1023;
            dst[(((size_t)(b * 8 + hh) * 1024 + n) * 64) + d] =
                __float2bfloat16(acc[cs][r] + bv);
        }
    }
}

// ---------------------------------------------------------------------------
// Kernel 3: attention, softmax over HEADS.  R11 = R5/R10 dataflow with
// SINGLE-buffered K_s.  Safety argument: all kf reads of iter i complete
// before the ns0-barrier; stage(i+1) is issued right after it (overwriting
// the same buffer is WAR-safe); the end-of-iter __syncthreads drains the DMA
// (RAW-safe for iter i+1's reads).  LDS 68KB = K 32 + P 20 + X 16 ->
// 2 blocks/CU (4 waves/SIMD) at __launch_bounds__(512,4); VGPR already 128.
// grid: (16 combos = b + 8*dir, 16 ntiles of 64 rows), XCD-local.
// ---------------------------------------------------------------------------
__global__ __launch_bounds__(512, 4) void attn_kernel(
    const __hip_bfloat16* __restrict__ Qn, const __hip_bfloat16* __restrict__ Kn,
    const __hip_bfloat16* __restrict__ Qr, const __hip_bfloat16* __restrict__ Kr,
    const __hip_bfloat16* __restrict__ Vtn, const __hip_bfloat16* __restrict__ Vtr,
    float* __restrict__ out)
{
    const int combo = blockIdx.x;     // 0..15
    const int bb    = combo & 7;
    const int dir   = combo >> 3;
    const int nt    = blockIdx.y;     // 0..15
    const __hip_bfloat16* Q  = dir ? Qr  : Qn;
    const __hip_bfloat16* K  = dir ? Kn  : Kr;
    const __hip_bfloat16* Vt = dir ? Vtn : Vtr;
    float* O = out + (size_t)dir * (8u * 1024u * 512u);

    const int t    = threadIdx.x;
    const int lane = t & 63;
    const int w    = t >> 6;          // 0..7
    const int iw   = w & 1;           // n-subtile within pair
    const int hg   = w >> 1;          // head pair 0..3
    const int h0   = hg * 2;
    const int l15  = lane & 15;
    const int lg   = lane >> 4;       // 0..3

    __shared__ short K_s[8 * 32 * 64];      // 32KB: [h][m][d] (slot-swizzled)
    __shared__ short P_s[8][32][40];        // 20KB, wave-private regions
    __shared__ float X_s[2][4][2][512];     // 16KB [ns][hg][iw][p*64+lane]

    const int n0 = nt * 64;
    const float C = 0.125f * 1.44269504f;   // SCALE * log2(e)

    const __hip_bfloat16* Vb[2] = {
        Vt + (size_t)((bb * 8 + h0)     * 64) * 1024,
        Vt + (size_t)((bb * 8 + h0 + 1) * 64) * 1024 };

    auto stage = [&](int mt) {
        #pragma unroll
        for (int i = 0; i < 4; ++i) {
            const int u    = (w * 4 + i) * 64 + lane;   // 16B unit, 0..2047
            const int h    = u >> 8;                    // 256 units per head
            const int mr   = (u >> 3) & 31;             // row within tile
            const int slot = (u & 7) ^ (mr & 7);        // swizzled 16B slot
            const __hip_bfloat16* g =
                K + ((size_t)((bb * 8 + h) * 1024) + mt + mr) * 64 + slot * 8;
            __builtin_amdgcn_global_load_lds(
                (const __attribute__((address_space(1))) unsigned int*)g,
                (__attribute__((address_space(3))) unsigned int*)&K_s[u * 8],
                16, 0, 0);
        }
    };

    // Q fragments (B operand): qf[ns][hh][kc]
    short8 qf[2][2][2];
    #pragma unroll
    for (int ns = 0; ns < 2; ++ns)
        #pragma unroll
        for (int hh = 0; hh < 2; ++hh)
            #pragma unroll
            for (int kc = 0; kc < 2; ++kc)
                qf[ns][hh][kc] = *reinterpret_cast<const short8*>(
                    Q + ((size_t)((bb * 8 + h0 + hh) * 1024) + n0 + ns * 32 + iw * 16 + l15) * 64
                      + kc * 32 + lg * 8);

    float4v oacc[2][2][4] = {};       // [ns][hh][dd]

    stage(0);
    __syncthreads();                  // drain prologue staging

    for (int it = 0; it < 32; ++it) {
        const int m0 = it << 5;
        // ---- V frags: issue early (global, consumed at PV) ----
        short8 vf[2][4];              // [hh][dd]
        #pragma unroll
        for (int hh = 0; hh < 2; ++hh)
            #pragma unroll
            for (int dd = 0; dd < 4; ++dd)
                vf[hh][dd] = *reinterpret_cast<const short8*>(
                    Vb[hh] + (size_t)(dd * 16 + l15) * 1024 + m0 + lg * 8);
        // ---- K frags from staged LDS (swizzled slots) ----
        short8 kf[2][2][2];           // [hh][j][kc]
        #pragma unroll
        for (int hh = 0; hh < 2; ++hh)
            #pragma unroll
            for (int j = 0; j < 2; ++j) {
                const int mr = j * 16 + l15;
                #pragma unroll
                for (int kc = 0; kc < 2; ++kc)
                    kf[hh][j][kc] = *reinterpret_cast<const short8*>(
                        K_s + (h0 + hh) * 2048 + mr * 64
                            + (((kc * 4 + lg) ^ (mr & 7)) * 8));
            }

        #pragma unroll
        for (int ns = 0; ns < 2; ++ns) {
            // ---- S^T = K Q^T, exp in-register ----
            float4v sacc[2][2] = {};  // [hh][j]
            #pragma unroll
            for (int hh = 0; hh < 2; ++hh)
                #pragma unroll
                for (int j = 0; j < 2; ++j)
                    #pragma unroll
                    for (int kc = 0; kc < 2; ++kc)
                        sacc[hh][j] = MFMA16(kf[hh][j][kc], qf[ns][hh][kc], sacc[hh][j]);
            float e[2][8];
            float ps[8] = {0.f, 0.f, 0.f, 0.f, 0.f, 0.f, 0.f, 0.f};
            #pragma unroll
            for (int hh = 0; hh < 2; ++hh)
                #pragma unroll
                for (int j = 0; j < 2; ++j)
                    #pragma unroll
                    for (int r = 0; r < 4; ++r) {
                        float ev = exp2f(sacc[hh][j][r] * C);
                        e[hh][j * 4 + r] = ev;
                        ps[j * 4 + r] += ev;
                    }
            // ---- exchange head-partial sums (scalar, conflict-free) ----
            #pragma unroll
            for (int p = 0; p < 8; ++p)
                X_s[ns][hg][iw][p * 64 + lane] = ps[p];
            __syncthreads();
            if (ns == 0)   // stage next iter's K into the SAME buffer
                stage((it < 31) ? m0 + 32 : 0);   // kf reads done before this barrier
            float inv[8];
            #pragma unroll
            for (int p = 0; p < 8; ++p) {
                float tot = ps[p];
                #pragma unroll
                for (int g = 1; g < 4; ++g)
                    tot += X_s[ns][(hg + g) & 3][iw][p * 64 + lane];
                inv[p] = __builtin_amdgcn_rcpf(tot);
            }
            // ---- P = e * inv -> wave-private P_s (b64 packed) ----
            #pragma unroll
            for (int hh = 0; hh < 2; ++hh)
                #pragma unroll
                for (int j = 0; j < 2; ++j) {
                    short4v pk;
                    #pragma unroll
                    for (int r = 0; r < 4; ++r)
                        pk[r] = f2bf(e[hh][j * 4 + r] * inv[j * 4 + r]);
                    *reinterpret_cast<short4v*>(
                        &P_s[h0 + hh][iw * 16 + l15][j * 16 + lg * 4]) = pk;
                }
            // ---- O += P V (P_s wave-private: in-wave LDS ordering suffices) ----
            #pragma unroll
            for (int hh = 0; hh < 2; ++hh) {
                short8 pf = *reinterpret_cast<const short8*>(
                    &P_s[h0 + hh][iw * 16 + l15][lg * 8]);
                #pragma unroll
                for (int dd = 0; dd < 4; ++dd)
                    oacc[ns][hh][dd] = MFMA16(pf, vf[hh][dd], oacc[ns][hh][dd]);
            }
        }
        __syncthreads();              // fences X slots + drains staging DMA
    }

    // ---- epilogue: O[b][n][h*64+d] f32 ----
    #pragma unroll
    for (int ns = 0; ns < 2; ++ns)
        #pragma unroll
        for (int hh = 0; hh < 2; ++hh)
            #pragma unroll
            for (int dd = 0; dd < 4; ++dd)
                #pragma unroll
                for (int r = 0; r < 4; ++r) {
                    const int n = n0 + ns * 32 + iw * 16 + lg * 4 + r;
                    const int d = dd * 16 + l15;
                    O[((size_t)(bb * 1024) + n) * 512 + (h0 + hh) * 64 + d] =
                        oacc[ns][hh][dd][r];
                }
}

extern "C" void kernel_launch(void* const* d_in, const int* in_sizes, int n_in,
                              void* d_out, int out_size, void* d_ws, size_t ws_size,
                              hipStream_t stream) {
    const float* nv = (const float*)d_in[0];
    const float* rv = (const float*)d_in[1];
    const float* Wn = (const float*)d_in[2];
    const float* bn = (const float*)d_in[3];
    const float* Wr = (const float*)d_in[4];
    const float* br = (const float*)d_in[5];
    float* out = (float*)d_out;

    __hip_bfloat16* w = (__hip_bfloat16*)d_ws;
    const size_t E = 8ull * 8 * 1024 * 64;    // 4M elems
    __hip_bfloat16* Qn  = w;
    __hip_bfloat16* Kn  = w + E;
    __hip_bfloat16* Qr  = w + 2 * E;
    __hip_bfloat16* Kr  = w + 3 * E;
    __hip_bfloat16* Vtn = w + 4 * E;
    __hip_bfloat16* Vtr = w + 5 * E;
    __hip_bfloat16* An  = w + 6 * E;
    __hip_bfloat16* Ar  = w + 7 * E;
    __hip_bfloat16* Wtn = w + 8 * E;
    __hip_bfloat16* Wtr = w + 8 * E + 512 * 1024;

    prep_kernel<<<dim3(32, 8, 9), 256, 0, stream>>>(nv, rv, Wn, Wr,
                                                    Vtn, Vtr, An, Ar, Wtn, Wtr);
    proj_kernel<<<dim3(128, 4, 2), 256, 0, stream>>>(An, Ar, Wtn, Wtr, bn, br,
                                                     Qn, Kn, Qr, Kr);
    attn_kernel<<<dim3(16, 16), 512, 0, stream>>>(Qn, Kn, Qr, Kr, Vtn, Vtr, out);
}